// Round 10
// baseline (11170.128 us; speedup 1.0000x reference)
//
#include <hip/hip_runtime.h>

#define NN 512
#define BB 64
#define TT 1000
#define NSL 4          // n-slices per batch-group
#define NBG 4          // batch-groups of 16

typedef unsigned int u32;
typedef unsigned short u16;
typedef unsigned long long u64;
typedef _Float16 h2_t __attribute__((ext_vector_type(2)));
typedef _Float16 f16x4 __attribute__((ext_vector_type(4)));
typedef float f32x4 __attribute__((ext_vector_type(4)));

__device__ inline u32 h2u(float a, float b) {
    h2_t h; h[0] = (_Float16)a; h[1] = (_Float16)b;
    return __builtin_bit_cast(u32, h);
}
__device__ inline f16x4 u2f(u32 lo, u32 hi) {
    uint2 v; v.x = lo; v.y = hi;
    return __builtin_bit_cast(f16x4, v);
}

// K=16 MFMA with fully-documented per-lane layout:
// A[l&15][(l>>4)*4+i], B[(l>>4)*4+i][l&15], D[(l>>4)*4+r][l&15].
__device__ inline f32x4 mfma16(f16x4 a, f16x4 b, f32x4 c) {
    return __builtin_amdgcn_mfma_f32_16x16x16f16(a, b, c, 0, 0, 0);
}

// ---------------------------------------------------------------------------
// Pack W into paired K=16 B-fragment lines. Line idx = ((s*8+w)*16 + kk)*64+l:
//   n = s*128 + w*16 + (l&15), kb = kk*32 + (l>>4)*4
//   v.xy = f16 pairs of W[n][kb..kb+3]     (k-slice kk*32 +  0..16)
//   v.zw = f16 pairs of W[n][kb+16..kb+19] (k-slice kk*32 + 16..32)
// ---------------------------------------------------------------------------
__global__ __launch_bounds__(256) void pack_wb(const float* __restrict__ W,
                                               uint4* __restrict__ wb) {
    const int idx = blockIdx.x * 256 + threadIdx.x;   // 0..32767
    const int l  = idx & 63;
    const int kk = (idx >> 6) & 15;
    const int w  = (idx >> 10) & 7;
    const int s  = idx >> 13;
    const int n  = s * 128 + w * 16 + (l & 15);
    const int kb = kk * 32 + ((l >> 4) << 2);
    const float* wr = W + (size_t)n * NN + kb;
    uint4 v;
    v.x = h2u(wr[0],  wr[1]);
    v.y = h2u(wr[2],  wr[3]);
    v.z = h2u(wr[16], wr[17]);
    v.w = h2u(wr[18], wr[19]);
    wb[idx] = v;
}

// ---------------------------------------------------------------------------
// Cooperating-slice MFMA scan: 16 active WGs = 4 batch-groups x 4 n-slices,
// 512 threads (8 waves). Wave w owns n-tile [s*128+w*16, +16) x its group's
// 16 batches. B-panel per lane = 16 uint4 (64 VGPR), pinned resident.
// Per step: 32 x mfma16 -> h update -> tanh -> mbox (agent atomics) ->
// flag release -> spin siblings -> reader fence -> assemble A-frags (LDS,
// double-buffered). W global traffic in the T-loop: zero.
// ---------------------------------------------------------------------------
__global__ __launch_bounds__(512) void rnn_scan(
        const float* __restrict__ h0v, const float* __restrict__ X,
        const uint4* __restrict__ wb, u16* __restrict__ mb,
        int* __restrict__ flags, float* __restrict__ hid) {
    const int wg = blockIdx.x;
    const int bg = wg & 7;
    const int s  = wg >> 3;
    if (bg >= NBG) return;

    const int tid = threadIdx.x;
    const int w = tid >> 6;
    const int l = tid & 63;

    __shared__ uint4 af[2][16][64];   // paired A-fragments, dbuf (32 KB)

    // ---- B-fragments: 16 uint4 = 64 VGPRs/lane ----
    uint4 bf[16];
    const uint4* wbp = wb + ((size_t)(s * 8 + w) * 16) * 64 + l;
#pragma unroll
    for (int kk = 0; kk < 16; ++kk) bf[kk] = wbp[kk * 64];

    // ---- A-frag init from tanh(h0) (batch-broadcast) ----
    for (int q = tid; q < 1024; q += 512) {
        const int kk = q >> 6, ll = q & 63;
        const int k0 = kk * 32 + ((ll >> 4) << 2);
        uint4 v;
        v.x = h2u(tanhf(h0v[k0 + 0]),  tanhf(h0v[k0 + 1]));
        v.y = h2u(tanhf(h0v[k0 + 2]),  tanhf(h0v[k0 + 3]));
        v.z = h2u(tanhf(h0v[k0 + 16]), tanhf(h0v[k0 + 17]));
        v.w = h2u(tanhf(h0v[k0 + 18]), tanhf(h0v[k0 + 19]));
        af[0][kk][ll] = v;
    }

    // ---- per-lane state: column nl, 4 batch rows (D rows (l>>4)*4+r) ----
    const int nl = s * 128 + w * 16 + (l & 15);
    const int b0 = bg * 16 + ((l >> 4) << 2);
    float h4[4];
    { const float hv = h0v[nl]; h4[0] = h4[1] = h4[2] = h4[3] = hv; }
    const float* xq0 = X + (size_t)(b0 + 0) * TT * NN + nl;
    const float* xq1 = X + (size_t)(b0 + 1) * TT * NN + nl;
    const float* xq2 = X + (size_t)(b0 + 2) * TT * NN + nl;
    const float* xq3 = X + (size_t)(b0 + 3) * TT * NN + nl;
    float xv[4] = {*xq0, *xq1, *xq2, *xq3};
    float* hq = hid + (size_t)b0 * NN + nl;

    u16* const mbg = mb + (size_t)bg * 2 * 16 * NN;   // [buf][16][512]
    int* const flgbase = flags + bg * NSL * 32;

    __syncthreads();

    for (int t = 0; t < TT; ++t) {
        const int cur = t & 1, nxt = cur ^ 1;

        // zero-cost residency pin (r3-r7 lesson: unpinned W arrays get sunk)
#pragma unroll
        for (int kk = 0; kk < 16; ++kk)
            asm volatile("" : "+v"(bf[kk].x), "+v"(bf[kk].y), "+v"(bf[kk].z), "+v"(bf[kk].w));

        f32x4 acc = {0.f, 0.f, 0.f, 0.f};
#pragma unroll
        for (int kk = 0; kk < 16; ++kk) {
            const uint4 av = af[cur][kk][l];
            const uint4 bv = bf[kk];
            acc = mfma16(u2f(av.x, av.y), u2f(bv.x, bv.y), acc);
            acc = mfma16(u2f(av.z, av.w), u2f(bv.z, bv.w), acc);
        }

        // prefetch x(t+1)
        float xn[4] = {0.f, 0.f, 0.f, 0.f};
        if (t + 1 < TT) {
            xn[0] = xq0[(size_t)(t + 1) * NN];
            xn[1] = xq1[(size_t)(t + 1) * NN];
            xn[2] = xq2[(size_t)(t + 1) * NN];
            xn[3] = xq3[(size_t)(t + 1) * NN];
        }

        float th4[4];
#pragma unroll
        for (int r = 0; r < 4; ++r) {
            const float hn = 0.9f * h4[r] + 0.1f * (acc[r] + xv[r]);
            h4[r] = hn;
            hq[r * NN] = hn;
            th4[r] = tanhf(hn);
            xv[r] = xn[r];
        }
        hq += (size_t)BB * NN;

        // mbox: even (l&15) lanes store (nl, nl+1) f16 pairs, 4 batch rows
        u16* const mbuf = mbg + (size_t)nxt * 16 * NN;
#pragma unroll
        for (int r = 0; r < 4; ++r) {
            const float nb = __shfl_down(th4[r], 1);
            if (((l & 15) & 1) == 0) {
                const u32 pk = h2u(th4[r], nb);
                u32* dst = (u32*)(mbuf + ((size_t)(((l >> 4) << 2) + r)) * NN + nl);
                __hip_atomic_store(dst, pk, __ATOMIC_RELAXED, __HIP_MEMORY_SCOPE_AGENT);
            }
        }

        __threadfence();
        __syncthreads();
        if (tid == 0)
            __hip_atomic_store(&flgbase[s * 32], t + 1, __ATOMIC_RELEASE, __HIP_MEMORY_SCOPE_AGENT);
        if (tid < NSL) {
            while (__hip_atomic_load(&flgbase[tid * 32], __ATOMIC_ACQUIRE,
                                     __HIP_MEMORY_SCOPE_AGENT) < t + 1) {}
        }
        __syncthreads();
        __threadfence();   // reader-side: order assembly loads after the acquire

        // assemble next A-frags: line (kk,ll) = batch bl=ll&15,
        // k = kk*32 + (ll>>4)*4 (+16 for the hi pair)
        for (int q = tid; q < 1024; q += 512) {
            const int kk = q >> 6, ll = q & 63;
            const int bl = ll & 15;
            const int k0 = kk * 32 + ((ll >> 4) << 2);
            const u64* s0 = (const u64*)(mbuf + (size_t)bl * NN + k0);
            const u64* s1 = (const u64*)(mbuf + (size_t)bl * NN + k0 + 16);
            const u64 lo = __hip_atomic_load(s0, __ATOMIC_RELAXED, __HIP_MEMORY_SCOPE_AGENT);
            const u64 hi = __hip_atomic_load(s1, __ATOMIC_RELAXED, __HIP_MEMORY_SCOPE_AGENT);
            af[nxt][kk][ll] = make_uint4((u32)lo, (u32)(lo >> 32), (u32)hi, (u32)(hi >> 32));
        }
        __syncthreads();
    }
}

// ---------------------------------------------------------------------------
// geometry = tanh(hidden_t) @ G_w.T + G_b ; readout = geometry @ D.T
// ---------------------------------------------------------------------------
__global__ __launch_bounds__(256) void geo_read(const float* __restrict__ hid,
                                                const float* __restrict__ Gw,
                                                const float* __restrict__ Gb,
                                                float* __restrict__ geo,
                                                float* __restrict__ rdo) {
    const int wave = (int)((blockIdx.x * 256 + threadIdx.x) >> 6);  // 0..63999
    const int lane = threadIdx.x & 63;
    if (wave >= TT * BB) return;

    const float* hrow = hid + (size_t)wave * NN;
    float g0 = 0.f, g1 = 0.f;
#pragma unroll
    for (int i = 0; i < 2; ++i) {
        const int off = i * 256 + lane * 4;
        const float4 hv = *reinterpret_cast<const float4*>(hrow + off);
        const float4 w0 = *reinterpret_cast<const float4*>(Gw + off);
        const float4 w1 = *reinterpret_cast<const float4*>(Gw + NN + off);
        const float t0 = tanhf(hv.x), t1 = tanhf(hv.y), t2 = tanhf(hv.z), t3 = tanhf(hv.w);
        g0 = fmaf(t0, w0.x, fmaf(t1, w0.y, fmaf(t2, w0.z, fmaf(t3, w0.w, g0))));
        g1 = fmaf(t0, w1.x, fmaf(t1, w1.y, fmaf(t2, w1.z, fmaf(t3, w1.w, g1))));
    }
#pragma unroll
    for (int off = 32; off > 0; off >>= 1) {
        g0 += __shfl_down(g0, off);
        g1 += __shfl_down(g1, off);
    }
    if (lane == 0) {
        g0 += Gb[0];
        g1 += Gb[1];
        geo[(size_t)wave * 2 + 0] = g0;
        geo[(size_t)wave * 2 + 1] = g1;
        const float dc[6] = {1.0f, 0.5f, -0.5f, -1.0f, -0.5f, 0.5f};
        const float ds[6] = {0.0f, 0.86602540378443865f, 0.86602540378443871f,
                             1.2246467991473532e-16f, -0.86602540378443837f,
                             -0.86602540378443860f};
#pragma unroll
        for (int k = 0; k < 6; ++k)
            rdo[(size_t)wave * 6 + k] = fmaf(g0, dc[k], g1 * ds[k]);
    }
}

extern "C" void kernel_launch(void* const* d_in, const int* in_sizes, int n_in,
                              void* d_out, int out_size, void* d_ws, size_t ws_size,
                              hipStream_t stream) {
    const float* h0 = (const float*)d_in[0];   // [512]
    const float* X  = (const float*)d_in[1];   // [64,1000,512]
    const float* W  = (const float*)d_in[2];   // [512,512]
    const float* Gw = (const float*)d_in[3];   // [2,512]
    const float* Gb = (const float*)d_in[4];   // [2]

    float* out = (float*)d_out;
    float* hid = out;                                   // [T*B*N]
    float* geo = out + (size_t)TT * BB * NN;            // [T*B*2]
    float* rdo = geo + (size_t)TT * BB * 2;             // [T*B*6]

    // Scratch: wb (512 KB) + mbox (128 KB) + flags (2 KB).
    const size_t wb_bytes = (size_t)32768 * 16;             // 512 KB
    const size_t mb_bytes = (size_t)NBG * 2 * 16 * NN * 2;  // 128 KB
    const size_t fl_bytes = (size_t)NBG * NSL * 32 * 4;     // 2 KB
    const size_t need = wb_bytes + mb_bytes + fl_bytes;
    char* base = (ws_size >= need) ? (char*)d_ws : (char*)geo;
    uint4* wbuf = (uint4*)base;
    u16*   mbb  = (u16*)(base + wb_bytes);
    int*   flg  = (int*)(base + wb_bytes + mb_bytes);

    (void)hipMemsetAsync(flg, 0, fl_bytes, stream);     // replay-deterministic
    pack_wb<<<128, 256, 0, stream>>>(W, wbuf);
    rnn_scan<<<28, 512, 0, stream>>>(h0, X, wbuf, mbb, flg, hid);
    geo_read<<<(TT * BB) / 4, 256, 0, stream>>>(hid, Gw, Gb, geo, rdo);
}

// Round 11
// 2214.865 us; speedup vs baseline: 5.0433x; 5.0433x over previous
//
#include <hip/hip_runtime.h>

#define NN 512
#define BB 64
#define TT 1000

typedef unsigned int u32;
typedef _Float16 h2_t __attribute__((ext_vector_type(2)));

// acc += s[0]*w[0] + s[1]*w[1]  (f16 inputs, f32 accumulate) — v_dot2_f32_f16
__device__ inline float fdot2(u32 su, u32 wu, float acc) {
#if __has_builtin(__builtin_amdgcn_fdot2)
    return __builtin_amdgcn_fdot2(__builtin_bit_cast(h2_t, su),
                                  __builtin_bit_cast(h2_t, wu), acc, false);
#else
    h2_t s = __builtin_bit_cast(h2_t, su);
    h2_t w = __builtin_bit_cast(h2_t, wu);
    return fmaf((float)s[0], (float)w[0], fmaf((float)s[1], (float)w[1], acc));
#endif
}

__device__ inline u32 h2pack(float a, float b) {
    h2_t h;
    h[0] = (_Float16)a;
    h[1] = (_Float16)b;
    return __builtin_bit_cast(u32, h);
}

// ---------------------------------------------------------------------------
// Pack W f32 [n][k] -> wpk[(ks*32+j)*256 + c] uint4, kp = ks*64 + 2j:
//   .x = h2(W[2c  ][2kp],   W[2c  ][2kp+1])
//   .y = h2(W[2c+1][2kp],   W[2c+1][2kp+1])
//   .z = h2(W[2c  ][2kp+2], W[2c  ][2kp+3])
//   .w = h2(W[2c+1][2kp+2], W[2c+1][2kp+3])
// (r7's layout — numerically validated there.)
// ---------------------------------------------------------------------------
__global__ __launch_bounds__(256) void pack_w(const float* __restrict__ W,
                                              uint4* __restrict__ wpk) {
    const int c = threadIdx.x;                       // 0..255
    const int blk = blockIdx.x;                      // 0..127 = ks*32+j
    const int kp = (blk >> 5) * 64 + (blk & 31) * 2;
    const int k0 = 2 * kp;
    const float* r0 = W + (size_t)(2 * c) * NN + k0;
    const float* r1 = W + (size_t)(2 * c + 1) * NN + k0;
    uint4 v;
    v.x = h2pack(r0[0], r0[1]);
    v.y = h2pack(r1[0], r1[1]);
    v.z = h2pack(r0[2], r0[3]);
    v.w = h2pack(r1[2], r1[3]);
    wpk[(size_t)blk * 256 + c] = v;
}

#define DOT8(s, wA, wB)                                           \
    a0 = fdot2((s).x, (wA).x, a0); a1 = fdot2((s).x, (wA).y, a1); \
    a0 = fdot2((s).y, (wA).z, a0); a1 = fdot2((s).y, (wA).w, a1); \
    a0 = fdot2((s).z, (wB).x, a0); a1 = fdot2((s).z, (wB).y, a1); \
    a0 = fdot2((s).w, (wB).z, a0); a1 = fdot2((s).w, (wB).w, a1);

// ---------------------------------------------------------------------------
// Persistent scan, one WG per batch (zero cross-WG traffic), 1024 threads
// (16 waves, 4/SIMD). Thread (ks=tid>>8, c=tid&255) owns k in
// [128ks, 128ks+128) x cols {2c, 2c+1} = 128 W-dwords, split three ways:
//   j  0..15 -> 16 uint4 VGPR-resident, volatile-pinned in-loop (the ONLY
//               pin variant proven to hold: r8-r10 VGPR=72, no W re-fetch;
//               prologue-pin (r4/5) spilled, non-volatile (r7) sank)
//   j 16..19 -> LDS-resident (64 KB/CU, loaded once)
//   j 20..31 -> streamed from L2 each step (192 KB; the allocator sinks
//               these unpinned loop-invariant loads under pressure — r3)
// Per step: tanh->LDS f16 | bar | 128 dot2/thread from 3 overlapping pipes
// | part | bar | 4-way k-reduce + h update + store.
// ---------------------------------------------------------------------------
__global__ __launch_bounds__(1024)
__attribute__((amdgpu_waves_per_eu(4, 4)))
void rnn_scan(const float* __restrict__ h0v,
              const float* __restrict__ X,
              const uint4* __restrict__ wpk,
              float* __restrict__ hid) {
    const int b = blockIdx.x;
    const int tid = threadIdx.x;
    const int c = tid & 255;
    const int ks = tid >> 8;

    __shared__ __attribute__((aligned(16))) unsigned short th_h[NN];  // 1 KB
    __shared__ uint4 wlds[4 * 1024];                                   // 64 KB
    __shared__ float2 part[4][256];                                    // 2 KB

    const uint4* wp = wpk + (size_t)(ks * 32) * 256 + c;

    // ---- prologue ----
    uint4 wreg[16];
#pragma unroll
    for (int j = 0; j < 16; ++j) wreg[j] = wp[j * 256];
#pragma unroll
    for (int j = 0; j < 4; ++j) wlds[j * 1024 + tid] = wp[(16 + j) * 256];

    const float* xb = X + (size_t)b * TT * NN;
    float h = 0.f, xn = 0.f;
    if (tid < NN) {
        h = h0v[tid];
        xn = xb[tid];
    }
    __syncthreads();

    const uint4* thv = reinterpret_cast<const uint4*>(th_h);  // [ks*16+p], wave-uniform
    const float* pf = reinterpret_cast<const float*>(part);   // pf[ks*512 + n]
    const uint4* wl = wlds + tid;                              // + j2*1024

    for (int t = 0; t < TT; ++t) {
        // residency pin: volatile redefinition each iteration (r8-proven)
#pragma unroll
        for (int j = 0; j < 16; ++j)
            asm volatile("" : "+v"(wreg[j].x), "+v"(wreg[j].y), "+v"(wreg[j].z), "+v"(wreg[j].w));

        if (tid < NN) {
            const _Float16 hh = (_Float16)tanhf(h);
            th_h[tid] = __builtin_bit_cast(unsigned short, hh);
        }
        __syncthreads();

        // x(t+1) prefetch — a full matvec of latency slack
        float xnext = (tid < NN && t + 1 < TT) ? xb[(size_t)(t + 1) * NN + tid] : 0.f;

        // stream group A issued before compute so L2 latency hides under dot2s
        const uint4 v0 = wp[20 * 256], v1 = wp[21 * 256],
                    v2 = wp[22 * 256], v3 = wp[23 * 256];

        float a0 = 0.f, a1 = 0.f;
        // --- VGPR pipe: p = 0..7 ---
#pragma unroll
        for (int p = 0; p < 8; ++p) {
            const uint4 s = thv[ks * 16 + p];   // same-addr broadcast: conflict-free
            DOT8(s, wreg[2 * p], wreg[2 * p + 1]);
        }
        const uint4 v4 = wp[24 * 256], v5 = wp[25 * 256],
                    v6 = wp[26 * 256], v7 = wp[27 * 256];
        // --- LDS pipe: p = 8..9 ---
        {
            const uint4 s8 = thv[ks * 16 + 8];
            const uint4 wA = wl[0 * 1024], wB = wl[1 * 1024];
            DOT8(s8, wA, wB);
            const uint4 s9 = thv[ks * 16 + 9];
            const uint4 wC = wl[2 * 1024], wD = wl[3 * 1024];
            DOT8(s9, wC, wD);
        }
        const uint4 v8 = wp[28 * 256], v9 = wp[29 * 256],
                    v10 = wp[30 * 256], v11 = wp[31 * 256];
        // --- stream pipe: p = 10..15 ---
        {
            const uint4 s10 = thv[ks * 16 + 10];
            DOT8(s10, v0, v1);
            const uint4 s11 = thv[ks * 16 + 11];
            DOT8(s11, v2, v3);
            const uint4 s12 = thv[ks * 16 + 12];
            DOT8(s12, v4, v5);
            const uint4 s13 = thv[ks * 16 + 13];
            DOT8(s13, v6, v7);
            const uint4 s14 = thv[ks * 16 + 14];
            DOT8(s14, v8, v9);
            const uint4 s15 = thv[ks * 16 + 15];
            DOT8(s15, v10, v11);
        }
        part[ks][c] = make_float2(a0, a1);
        __syncthreads();

        if (tid < NN) {
            const float sum = (pf[tid] + pf[512 + tid]) + (pf[1024 + tid] + pf[1536 + tid]);
            h = 0.9f * h + 0.1f * (sum + xn);
            hid[((size_t)t * BB + b) * NN + tid] = h;
            xn = xnext;
        }
        // 2-barrier scheme (r3-validated): next th_h write happens after bar2;
        // all thv reads of this step completed before part write -> bar2.
    }
}

// ---------------------------------------------------------------------------
// geometry = tanh(hidden_t) @ G_w.T + G_b ; readout = geometry @ D.T
// ---------------------------------------------------------------------------
__global__ __launch_bounds__(256) void geo_read(const float* __restrict__ hid,
                                                const float* __restrict__ Gw,
                                                const float* __restrict__ Gb,
                                                float* __restrict__ geo,
                                                float* __restrict__ rdo) {
    const int wave = (int)((blockIdx.x * 256 + threadIdx.x) >> 6);  // 0..63999
    const int lane = threadIdx.x & 63;
    if (wave >= TT * BB) return;

    const float* hrow = hid + (size_t)wave * NN;
    float g0 = 0.f, g1 = 0.f;
#pragma unroll
    for (int i = 0; i < 2; ++i) {
        const int off = i * 256 + lane * 4;
        const float4 hv = *reinterpret_cast<const float4*>(hrow + off);
        const float4 w0 = *reinterpret_cast<const float4*>(Gw + off);
        const float4 w1 = *reinterpret_cast<const float4*>(Gw + NN + off);
        const float t0 = tanhf(hv.x), t1 = tanhf(hv.y), t2 = tanhf(hv.z), t3 = tanhf(hv.w);
        g0 = fmaf(t0, w0.x, fmaf(t1, w0.y, fmaf(t2, w0.z, fmaf(t3, w0.w, g0))));
        g1 = fmaf(t0, w1.x, fmaf(t1, w1.y, fmaf(t2, w1.z, fmaf(t3, w1.w, g1))));
    }
#pragma unroll
    for (int off = 32; off > 0; off >>= 1) {
        g0 += __shfl_down(g0, off);
        g1 += __shfl_down(g1, off);
    }
    if (lane == 0) {
        g0 += Gb[0];
        g1 += Gb[1];
        geo[(size_t)wave * 2 + 0] = g0;
        geo[(size_t)wave * 2 + 1] = g1;
        const float dc[6] = {1.0f, 0.5f, -0.5f, -1.0f, -0.5f, 0.5f};
        const float ds[6] = {0.0f, 0.86602540378443865f, 0.86602540378443871f,
                             1.2246467991473532e-16f, -0.86602540378443837f,
                             -0.86602540378443860f};
#pragma unroll
        for (int k = 0; k < 6; ++k)
            rdo[(size_t)wave * 6 + k] = fmaf(g0, dc[k], g1 * ds[k]);
    }
}

extern "C" void kernel_launch(void* const* d_in, const int* in_sizes, int n_in,
                              void* d_out, int out_size, void* d_ws, size_t ws_size,
                              hipStream_t stream) {
    const float* h0 = (const float*)d_in[0];   // [512]
    const float* X  = (const float*)d_in[1];   // [64,1000,512]
    const float* W  = (const float*)d_in[2];   // [512,512]
    const float* Gw = (const float*)d_in[3];   // [2,512]
    const float* Gb = (const float*)d_in[4];   // [2]

    float* out = (float*)d_out;
    float* hid = out;                                   // [T*B*N]
    float* geo = out + (size_t)TT * BB * NN;            // [T*B*2]
    float* rdo = geo + (size_t)TT * BB * 2;             // [T*B*6]

    // Packed f16 W: 512 KB. Fallback: geo+rdo region (2 MB, overwritten later).
    const size_t wp_bytes = (size_t)NN * NN * sizeof(unsigned short);
    uint4* Wpk = (ws_size >= wp_bytes) ? (uint4*)d_ws : (uint4*)geo;

    pack_w<<<128, 256, 0, stream>>>(W, Wpk);
    rnn_scan<<<BB, 1024, 0, stream>>>(h0, X, Wpk, hid);
    geo_read<<<(TT * BB) / 4, 256, 0, stream>>>(hid, Gw, Gb, geo, rdo);
}